// Round 2
// baseline (2099.009 us; speedup 1.0000x reference)
//
#include <hip/hip_runtime.h>

// DynamicRouting: grouped 1x1 conv (G=8, FI=FO=64) + 3-iter sigmoid routing.
// Block = 512 threads = 8 waves, one WG per (b,h) row of 64 pixels.
// wave = group g (weight addrs wave-uniform -> scalar loads);
// thread (p = tid&63, g = tid>>6) owns con[64] (all fo for its group).
// 64 accumulators/thread -> no spill (round 1 spilled at 128 acc / 92 VGPR).
// Cross-group routing reduction via LDS ds_add_f32 into vbuf[f][p]
// (bank = p%32 -> 2-way aliasing, free).

#define NG 8
#define NFO 64
#define NFI 64
#define NB 32
#define NH 64
#define NW 64
#define HW (NH * NW)

__global__ __launch_bounds__(512) void dynrout_kernel(
    const float* __restrict__ x, const float* __restrict__ weight,
    const float* __restrict__ bias, float* __restrict__ out)
{
    const int tid = threadIdx.x;
    const int p = tid & 63;
    const int g = __builtin_amdgcn_readfirstlane(tid >> 6);  // wave-uniform group

    const int wg = blockIdx.x;
    const int b = wg >> 6;
    const int h = wg & 63;

    // x[b][g*64+i][h][w]; this thread reads channel i at xg[i*HW]
    const float* xg = x + ((size_t)(b * (NG * NFI) + g * NFI) * HW)
                        + (size_t)h * NW + p;
    const float* wgt = weight + (size_t)g * NFO * NFI;  // [fo][i], wave-uniform

    float con[64];
#pragma unroll
    for (int f = 0; f < 64; ++f) con[f] = 0.f;

    // ---- grouped 1x1 conv: con[f] = sum_i wgt[f][i] * xg[i] ----
#pragma unroll
    for (int ib = 0; ib < 4; ++ib) {
        float xv[16];
#pragma unroll
        for (int j = 0; j < 16; ++j)
            xv[j] = xg[(size_t)(ib * 16 + j) * HW];
#pragma unroll
        for (int f = 0; f < 64; ++f) {
            const float* wr = wgt + f * NFI + ib * 16;
#pragma unroll
            for (int j = 0; j < 16; ++j)
                con[f] = fmaf(wr[j], xv[j], con[f]);
        }
    }

    // ---- routing ----
    __shared__ float vbuf[NFO * NW];  // [f][p], 16 KB

    float beta = 0.f;
    float alpha = 0.5f;  // sigmoid(0)

#pragma unroll
    for (int it = 0; it < 3; ++it) {
        // zero the reduction buffer
        for (int k = tid; k < NFO * NW; k += 512) vbuf[k] = 0.f;
        __syncthreads();
        // v[f][p] += alpha_g * con_g[f]  (8 waves accumulate via ds_add_f32)
#pragma unroll
        for (int f = 0; f < 64; ++f)
            atomicAdd(&vbuf[f * NW + p], alpha * con[f]);
        __syncthreads();
        if (it < 2) {
            // beta_g[p] += sum_f v[f][p] * con_g[f]   (thread-private)
            float bsum = 0.f;
#pragma unroll
            for (int f = 0; f < 64; ++f)
                bsum = fmaf(vbuf[f * NW + p], con[f], bsum);
            beta += bsum;
            alpha = 1.f / (1.f + __expf(-beta));
            __syncthreads();  // all vbuf reads done before next zeroing
        }
    }

    // ---- epilogue: out[b][f][h][p] = v2[f][p] + bias[f], wave g stores f=g*8..g*8+7
#pragma unroll
    for (int k = 0; k < 8; ++k) {
        const int f = g * 8 + k;
        out[(((size_t)b * NFO + f) * NH + h) * NW + p] = vbuf[f * NW + p] + bias[f];
    }
}

extern "C" void kernel_launch(void* const* d_in, const int* in_sizes, int n_in,
                              void* d_out, int out_size, void* d_ws, size_t ws_size,
                              hipStream_t stream) {
    const float* x      = (const float*)d_in[0];
    const float* weight = (const float*)d_in[1];
    const float* bias   = (const float*)d_in[2];
    float* out = (float*)d_out;

    dynrout_kernel<<<dim3(NB * NH), dim3(512), 0, stream>>>(x, weight, bias, out);
}